// Round 4
// baseline (332.454 us; speedup 1.0000x reference)
//
#include <hip/hip_runtime.h>

// Inverse Haar 2D wavelet: in (16,12,512,512) f32 -> out (16,3,1024,1024) f32
// in viewed as (BC=48 groups) x (4 subbands A,Hh,V,D) x (512x512) planes.
// out[bc, 2h+0, 2w+0] = (A+Hh+V+D)*0.5
// out[bc, 2h+0, 2w+1] = (A+Hh-V-D)*0.5
// out[bc, 2h+1, 2w+0] = (A-Hh+V-D)*0.5
// out[bc, 2h+1, 2w+1] = (A-Hh-V+D)*0.5
//
// R2 layout (verified best): one thread owns 2 input columns (float2 per
// plane) -> exactly one float4 per output row. Loads are 8 B/lane contiguous
// (512 B/wave, full cache lines), stores 16 B/lane fully wave-contiguous
// (1024 B per store instruction).
//
// Journal:
//  - R2 nt-stores: REGRESSED ~10-15 µs (harness re-poison fill writes 768 MiB
//    per dispatch -> L3 can never hold the input; nt loses L2 write combining).
//    Do not reintroduce.
//  - R3 (this round): CHUNKED PERSISTENCE. Kernel portion ~83 µs = 4.85 TB/s
//    vs 6.3-6.7 TB/s demonstrated on this chip (copy / the fills themselves).
//    Theory: 24576 one-shot blocks = ~10k short-lived HBM streams, each block
//    retires after 8 KiB of writes and the replacement jumps far away -> DRAM
//    row-buffer thrash. Fix: 2048 fully-resident blocks (8/CU), each walking
//    12 CONSECUTIVE rows (24 KiB-sequential reads/plane, 96 KiB-sequential
//    writes). Per-iteration access shape byte-identical to the R2 kernel.

__global__ __launch_bounds__(256) void
witlayer_iwt_kernel(const float* __restrict__ in, float* __restrict__ out) {
    constexpr int W = 512;
    constexpr int PLANE = 512 * 512;             // 262144
    constexpr int OUT_PLANE = 1024 * 1024;       // 1048576
    constexpr int OUT_W = 1024;
    constexpr int ITER = 12;                     // 24576 virtual blocks / 2048

    const int f2 = threadIdx.x;                  // 0..255: float2 index in row
    int vb = blockIdx.x * ITER;                  // virtual block = (bc<<9)|h

    #pragma unroll 2
    for (int i = 0; i < ITER; ++i, ++vb) {
        const int h  = vb & 511;                 // 9 bits
        const int bc = vb >> 9;                  // 0..47

        const int in_off = h * W + f2 * 2;
        const float* base = in + (size_t)bc * 4 * PLANE + in_off;
        const float2 a  = *(const float2*)(base + 0 * PLANE);
        const float2 hh = *(const float2*)(base + 1 * PLANE);
        const float2 v  = *(const float2*)(base + 2 * PLANE);
        const float2 d  = *(const float2*)(base + 3 * PLANE);

        float4 r0, r1;
        r0.x = (a.x + hh.x + v.x + d.x) * 0.5f;
        r0.y = (a.x + hh.x - v.x - d.x) * 0.5f;
        r0.z = (a.y + hh.y + v.y + d.y) * 0.5f;
        r0.w = (a.y + hh.y - v.y - d.y) * 0.5f;
        r1.x = (a.x - hh.x + v.x - d.x) * 0.5f;
        r1.y = (a.x - hh.x - v.x + d.x) * 0.5f;
        r1.z = (a.y - hh.y + v.y - d.y) * 0.5f;
        r1.w = (a.y - hh.y - v.y + d.y) * 0.5f;

        float* orow = out + (size_t)bc * OUT_PLANE + (size_t)(2 * h) * OUT_W;
        ((float4*)orow)[f2] = r0;                // row 2h
        ((float4*)(orow + OUT_W))[f2] = r1;      // row 2h+1
    }
}

extern "C" void kernel_launch(void* const* d_in, const int* in_sizes, int n_in,
                              void* d_out, int out_size, void* d_ws, size_t ws_size,
                              hipStream_t stream) {
    const float* in = (const float*)d_in[0];
    float* out = (float*)d_out;
    const int block = 256;
    const int grid = 2048;                       // 8 blocks/CU x 256 CUs, fully resident
    witlayer_iwt_kernel<<<grid, block, 0, stream>>>(in, out);
}

// Round 5
// 323.720 us; speedup vs baseline: 1.0270x; 1.0270x over previous
//
#include <hip/hip_runtime.h>

// Inverse Haar 2D wavelet: in (16,12,512,512) f32 -> out (16,3,1024,1024) f32
// in viewed as (BC=48 groups) x (4 subbands A,Hh,V,D) x (512x512) planes.
// out[bc, 2h+0, 2w+0] = (A+Hh+V+D)*0.5
// out[bc, 2h+0, 2w+1] = (A+Hh-V-D)*0.5
// out[bc, 2h+1, 2w+0] = (A-Hh+V-D)*0.5
// out[bc, 2h+1, 2w+1] = (A-Hh-V+D)*0.5
//
// R2 layout (verified best, 324.7/325.5 µs reproducible ±0.8): one thread owns
// 2 input columns (float2 per plane) -> exactly one float4 per output row.
// Loads 8 B/lane contiguous (512 B/wave, full cache lines), stores 16 B/lane
// fully wave-contiguous (1024 B per store instruction). One-shot blocks in
// dispatch order = sequential address sweep.
//
// Journal (do-not-retry list):
//  - nt-stores (R2 attempt): REGRESSED +7-15 µs. Harness re-poison writes
//    768 MiB/dispatch between iterations -> input can never stay L3-resident;
//    nt only loses L2 write combining.
//  - Chunked persistence 2048 blocks x 12 rows (R4): REGRESSED +7 µs.
//    vb = blockIdx*ITER spreads resident blocks 12x wider in address space;
//    in-order one-shot dispatch already gives the best DRAM locality.
//  - Half-dense stores (pre-session): worse; keep thread->2-cols mapping.
// Decomposition: timed graph = 2x 768 MiB poison fills (~243 µs, fixed) +
// kernel ~80-85 µs vs 64 µs copy-ceiling floor for 402.7 MB mixed traffic.

__global__ __launch_bounds__(256) void
witlayer_iwt_kernel(const float* __restrict__ in, float* __restrict__ out) {
    constexpr int W = 512;
    constexpr int W2 = W / 2;                    // 256 float2 per input row
    constexpr int PLANE = 512 * 512;             // 262144
    constexpr int OUT_PLANE = 1024 * 1024;       // 1048576
    constexpr int OUT_W = 1024;

    const int tid = blockIdx.x * blockDim.x + threadIdx.x;
    // total threads = 48 * 512 * 256 = 6,291,456
    const int f2 = tid & (W2 - 1);               // 8 bits: float2 index in row
    const int h  = (tid >> 8) & 511;             // 9 bits
    const int bc = tid >> 17;                    // 0..47

    const int in_off = h * W + f2 * 2;
    const float* base = in + (size_t)bc * 4 * PLANE + in_off;
    const float2 a  = *(const float2*)(base + 0 * PLANE);
    const float2 hh = *(const float2*)(base + 1 * PLANE);
    const float2 v  = *(const float2*)(base + 2 * PLANE);
    const float2 d  = *(const float2*)(base + 3 * PLANE);

    float4 r0, r1;
    r0.x = (a.x + hh.x + v.x + d.x) * 0.5f;
    r0.y = (a.x + hh.x - v.x - d.x) * 0.5f;
    r0.z = (a.y + hh.y + v.y + d.y) * 0.5f;
    r0.w = (a.y + hh.y - v.y - d.y) * 0.5f;
    r1.x = (a.x - hh.x + v.x - d.x) * 0.5f;
    r1.y = (a.x - hh.x - v.x + d.x) * 0.5f;
    r1.z = (a.y - hh.y + v.y - d.y) * 0.5f;
    r1.w = (a.y - hh.y - v.y + d.y) * 0.5f;

    float* orow = out + (size_t)bc * OUT_PLANE + (size_t)(2 * h) * OUT_W;
    ((float4*)orow)[f2] = r0;                    // row 2h
    ((float4*)(orow + OUT_W))[f2] = r1;          // row 2h+1
}

extern "C" void kernel_launch(void* const* d_in, const int* in_sizes, int n_in,
                              void* d_out, int out_size, void* d_ws, size_t ws_size,
                              hipStream_t stream) {
    const float* in = (const float*)d_in[0];
    float* out = (float*)d_out;
    const int total_threads = 48 * 512 * 256;    // 6,291,456
    const int block = 256;
    const int grid = total_threads / block;      // 24576
    witlayer_iwt_kernel<<<grid, block, 0, stream>>>(in, out);
}